// Round 3
// baseline (2279.275 us; speedup 1.0000x reference)
//
#include <hip/hip_runtime.h>
#include <hip/hip_bf16.h>
#include <stdint.h>

// ---------------------------------------------------------------------------
// EncoderBiLSTM on MI355X.
// RESET=32 => 16 independent chunks of 32 steps => 1024 independent rows/dir.
// Rows r = chunk*64 + b, t = chunk*32 + s.
// Per step, per layer: gates = [x_t | h] @ [Wih' | Whh']^T + bias (K=1536),
// fused fp16-MFMA GEMM (16x16x32) + in-epilogue LSTM cell update.
// Gate permutation: n = (j>>4)*64 + g*16 + (j&15), g in {i,f,g,o}
//   => within a 64-col group: 16 j's, gate-major => cell update is in-lane.
//
// Layer pipelining: launch k runs {L0 step k} || {L1 step k-1} (gridDim.z=2).
// L1 step s needs out0 rows t==s (mod 32) written by L0 step s (previous
// launch) -- disjoint from the t==k rows L0 writes this launch => race-free.
// 33 launches instead of 64; 512 blocks = 2 blocks/CU = 4 waves/SIMD.
// XCD = linear_block_id % 8 = nb % 8 => each XCD sees 8 weight panels
// (4 nb x 2 layers) ~= 3.1 MB -> L2-resident across all step launches.
// ---------------------------------------------------------------------------

typedef _Float16 half8 __attribute__((ext_vector_type(8)));
typedef _Float16 half4v __attribute__((ext_vector_type(4)));
typedef float float4v __attribute__((ext_vector_type(4)));

#define AS1C(p) ((const __attribute__((address_space(1))) void*)(p))
#define AS3(p)  ((__attribute__((address_space(3))) void*)(p))

__device__ __forceinline__ float sigm(float x){ return 1.0f/(1.0f + __expf(-x)); }
__device__ __forceinline__ float tanh_f(float x){ return 2.0f/(1.0f + __expf(-2.0f*x)) - 1.0f; }

// ---- embedding: emb[t][b][d] = (Ert[rt]+Ere[re]+Erm[rm]) as fp16 -----------
__global__ __launch_bounds__(256) void k_embed(
    const int* __restrict__ rt, const int* __restrict__ re, const int* __restrict__ rm,
    const float* __restrict__ Ert, const float* __restrict__ Ere, const float* __restrict__ Erm,
    _Float16* __restrict__ emb)
{
  size_t idx = (size_t)blockIdx.x * 256 + threadIdx.x;   // B*T*256 float4-units
  int dq = (int)(idx & 255);
  size_t bt = idx >> 8;                                  // b*512 + t
  int b = (int)(bt >> 9);
  int t = (int)(bt & 511);
  int irt = rt[bt], ire = re[bt], irm = rm[bt];
  float4 v0 = ((const float4*)Ert)[(size_t)irt * 256 + dq];
  float4 v1 = ((const float4*)Ere)[(size_t)ire * 256 + dq];
  float4 v2 = ((const float4*)Erm)[(size_t)irm * 256 + dq];
  half4v h;
  h[0] = (_Float16)(v0.x + v1.x + v2.x);
  h[1] = (_Float16)(v0.y + v1.y + v2.y);
  h[2] = (_Float16)(v0.z + v1.z + v2.z);
  h[3] = (_Float16)(v0.w + v1.w + v2.w);
  ((half4v*)emb)[((size_t)t * 64 + b) * 256 + dq] = h;
}

// ---- weight prep: Wc[ld][n][k] fp16, k<1024 from Wih, else Whh; n permuted -
__global__ __launch_bounds__(256) void k_prepw(
    const float* __restrict__ Wih, const float* __restrict__ Whh,
    _Float16* __restrict__ Wc)
{
  int bid = blockIdx.x;            // 0..8191  = ld*2048 + n
  int ld = bid >> 11;
  int n  = bid & 2047;
  int g  = (n >> 4) & 3;
  int j  = ((n >> 6) << 4) | (n & 15);
  int srow = g * 512 + j;
  const float* sx = Wih + ((size_t)ld * 2048 + srow) * 1024;
  const float* sh = Whh + ((size_t)ld * 2048 + srow) * 512;
  _Float16* dst = Wc + ((size_t)ld * 2048 + n) * 1536;
  for (int k = threadIdx.x; k < 1536; k += 256)
    dst[k] = (_Float16)(k < 1024 ? sx[k] : sh[k - 1024]);
}

__global__ __launch_bounds__(256) void k_prepb(
    const float* __restrict__ bih, const float* __restrict__ bhh,
    float* __restrict__ biasc)
{
  int idx = blockIdx.x * 256 + threadIdx.x;   // 8192
  int ld = idx >> 11, n = idx & 2047;
  int g = (n >> 4) & 3;
  int j = ((n >> 6) << 4) | (n & 15);
  int srow = ld * 2048 + g * 512 + j;
  biasc[idx] = bih[srow] + bhh[srow];
}

// ---- state init per layer: chunk0 rows from h0/c0, rest zero ---------------
__global__ __launch_bounds__(256) void k_init(
    int layer, const float* __restrict__ h0, const float* __restrict__ c0,
    _Float16* __restrict__ hbuf, float* __restrict__ cbuf)
{
  int idx = blockIdx.x * 256 + threadIdx.x;   // 2*1024*512
  int dir = idx >> 19;
  int rj = idx & ((1 << 19) - 1);
  int r = rj >> 9, j = rj & 511;
  float hv = 0.f, cv = 0.f;
  if (r < 64) {
    size_t s0 = ((size_t)(layer * 2 + dir) * 64 + r) * 512 + j;
    hv = h0[s0]; cv = c0[s0];
  }
  hbuf[idx] = (_Float16)hv;
  cbuf[idx] = cv;
}

// ---- fused step: GEMM(K=1536) + LSTM cell update ---------------------------
// grid (32, 8, 2): x = nb (dir*16 + ntile), y = M-tile (128 rows), z = layer.
// z=0 runs step s0 of layer 0; z=1 runs step s1 of layer 1 (skip if out of
// range). 512 threads = 8 waves: wm = w>>1 (rows), wn = w&1 (64-col group).
__global__ __launch_bounds__(512, 4) void k_step(
    int s0, int s1,
    const _Float16* __restrict__ emb,    // [T*B][1024]
    _Float16* __restrict__ out0,         // [T*B][1024] (L0 dest / L1 src, fp16)
    float* __restrict__ outs,            // [B][T][1024] (L1 dest, fp32)
    _Float16* __restrict__ hbAll,        // 4 buffers: (layer*2+parity)*2^20 halves
    float* __restrict__ cbAll,           // 2 buffers: layer*2^20 floats
    const _Float16* __restrict__ Wc,     // [4][2048][1536]
    const float* __restrict__ biasc,     // [4][2048]
    float* __restrict__ hT, float* __restrict__ cT)
{
  const int layer = blockIdx.z;
  const int s = layer ? s1 : s0;
  if ((unsigned)s > 31u) return;         // boundary launches idle one z-half

  const _Float16* xsrc = layer ? out0 : emb;
  const _Float16* hin  = hbAll + ((size_t)(layer * 2 + (s & 1))) * 1048576;
  _Float16*       hout = hbAll + ((size_t)(layer * 2 + ((s & 1) ^ 1))) * 1048576;
  float*          cbuf = cbAll + (size_t)layer * 1048576;

  // 64 KiB LDS: two 32 KiB buffers; within a buffer: A [0,16K) B [16K,32K) bytes
  __shared__ __align__(16) _Float16 smem[32768];
  const int tid = threadIdx.x;
  const int w = tid >> 6, l = tid & 63;
  const int nb = blockIdx.x;
  const int m0 = blockIdx.y * 128;
  const int dir = nb >> 4;
  const int n0 = (nb & 15) * 128;
  const int ld = layer * 2 + dir;

  // staging descriptors: 32 wave-instrs (16 A + 16 B), 4 per wave.
  // LDS layout k-chunk-major: chunk c = kc*128 + row (16B each) -> byte c*16.
  const char* pX[4]; const char* pH[4]; uint32_t ldsoff[4];
  #pragma unroll
  for (int ii = 0; ii < 4; ++ii) {
    int instr = w * 4 + ii;
    if (instr < 16) {                       // A tile: 1024 chunks
      int c = instr * 64 + l;
      int row = c & 127, kc = c >> 7;
      int r = m0 + row;
      int erow = ((r >> 6) * 32 + s) * 64 + (r & 63);     // t*64 + b
      pX[ii] = (const char*)(xsrc + (size_t)erow * 1024 + kc * 8);
      // h-phase: global k maps to h col k-1024 => pre-bias ptr by -1024 halfs
      pH[ii] = (const char*)(hin + ((size_t)dir * 1024 + r) * 512 + kc * 8) - 2048;
      ldsoff[ii] = (uint32_t)instr * 1024u;
    } else {                                // B tile: 1024 chunks
      int c = (instr - 16) * 64 + l;
      int nl = c & 127, kc = c >> 7;
      const char* p = (const char*)(Wc + ((size_t)ld * 2048 + n0 + nl) * 1536 + kc * 8);
      pX[ii] = p; pH[ii] = p;              // weight rows contiguous over full K
      ldsoff[ii] = 16384u + (uint32_t)(instr - 16) * 1024u;
    }
  }

  const int wm = w >> 1, wn = w & 1;
  float4v acc[2][4];
  const float4v vzero = {0.f, 0.f, 0.f, 0.f};
  #pragma unroll
  for (int mf = 0; mf < 2; ++mf)
    #pragma unroll
    for (int nf = 0; nf < 4; ++nf) acc[mf][nf] = vzero;

  auto stage = [&](int it, int buf) {
    const int k0 = it * 64;
    const bool isx = (it < 16);
    #pragma unroll
    for (int ii = 0; ii < 4; ++ii) {
      const char* src = (isx ? pX[ii] : pH[ii]) + (size_t)k0 * 2;
      __builtin_amdgcn_global_load_lds(AS1C(src),
          AS3(((char*)smem) + (size_t)buf * 32768 + ldsoff[ii]), 16, 0, 0);
    }
  };

  // T3 minimum 2-phase: stage(t+1) || compute(t); one barrier per tile.
  stage(0, 0);
  __syncthreads();                           // drains vmcnt before barrier
  #pragma unroll 2
  for (int it = 0; it < 24; ++it) {
    const int cur = it & 1;
    if (it + 1 < 24) stage(it + 1, cur ^ 1);
    const _Float16* sA = smem + (size_t)cur * 16384;
    const _Float16* sB = sA + 8192;
    #pragma unroll
    for (int kk = 0; kk < 64; kk += 32) {
      const int kcb = (kk >> 3) + (l >> 4);  // k-chunk for this lane
      half8 a[2], b[4];
      #pragma unroll
      for (int mf = 0; mf < 2; ++mf)
        a[mf] = *(const half8*)(sA + ((size_t)kcb * 128 + wm * 32 + mf * 16 + (l & 15)) * 8);
      #pragma unroll
      for (int nf = 0; nf < 4; ++nf)
        b[nf] = *(const half8*)(sB + ((size_t)kcb * 128 + wn * 64 + nf * 16 + (l & 15)) * 8);
      #pragma unroll
      for (int mf = 0; mf < 2; ++mf)
        #pragma unroll
        for (int nf = 0; nf < 4; ++nf)
          acc[mf][nf] = __builtin_amdgcn_mfma_f32_16x16x32_f16(a[mf], b[nf], acc[mf][nf], 0, 0, 0);
    }
    __syncthreads();                         // one full drain + barrier per tile
  }

  // ---- epilogue: gates are in-lane (nf = gate), j = q*16 + (l&15) ----------
  const int q = (nb & 15) * 2 + wn;
  const int jj = l & 15;
  const int j = q * 16 + jj;
  const int bb_base = ld * 2048 + n0 + wn * 64;
  const float bias_i = biasc[bb_base + 0 * 16 + jj];
  const float bias_f = biasc[bb_base + 1 * 16 + jj];
  const float bias_g = biasc[bb_base + 2 * 16 + jj];
  const float bias_o = biasc[bb_base + 3 * 16 + jj];

  #pragma unroll
  for (int mf = 0; mf < 2; ++mf) {
    #pragma unroll
    for (int reg = 0; reg < 4; ++reg) {
      int r = m0 + wm * 32 + mf * 16 + (l >> 4) * 4 + reg;   // C/D row mapping
      float ip = acc[mf][0][reg] + bias_i;
      float fp = acc[mf][1][reg] + bias_f;
      float gp = acc[mf][2][reg] + bias_g;
      float op = acc[mf][3][reg] + bias_o;
      size_t cidx = ((size_t)dir * 1024 + r) * 512 + j;
      float cold = cbuf[cidx];
      float cn = sigm(fp) * cold + sigm(ip) * tanh_f(gp);
      float hn = sigm(op) * tanh_f(cn);
      cbuf[cidx] = cn;
      hout[cidx] = (_Float16)hn;
      int chunk = r >> 6, bb = r & 63;
      int t = chunk * 32 + s;
      if (layer == 0) {
        out0[((size_t)t * 64 + bb) * 1024 + dir * 512 + j] = (_Float16)hn;
      } else {
        outs[((size_t)bb * 512 + t) * 1024 + dir * 512 + j] = hn;
      }
      if (s == 31 && chunk == 15) {          // final carry -> hidden outputs
        size_t hidx = ((size_t)(layer * 2 + dir) * 64 + bb) * 512 + j;
        hT[hidx] = hn; cT[hidx] = cn;
      }
    }
  }
}

// ---------------------------------------------------------------------------
extern "C" void kernel_launch(void* const* d_in, const int* in_sizes, int n_in,
                              void* d_out, int out_size, void* d_ws, size_t ws_size,
                              hipStream_t stream)
{
  const int*   rt  = (const int*)d_in[0];
  const int*   re  = (const int*)d_in[1];
  const int*   rm  = (const int*)d_in[2];
  const float* h0  = (const float*)d_in[3];
  const float* c0  = (const float*)d_in[4];
  const float* Ert = (const float*)d_in[5];
  const float* Ere = (const float*)d_in[6];
  const float* Erm = (const float*)d_in[7];
  const float* Wih = (const float*)d_in[8];
  const float* Whh = (const float*)d_in[9];
  const float* bih = (const float*)d_in[10];
  const float* bhh = (const float*)d_in[11];

  float* outs = (float*)d_out;                       // [B][T][D]
  float* hT = outs + (size_t)64 * 512 * 1024;        // [4][B][H]
  float* cT = hT + (size_t)4 * 64 * 512;             // [4][B][H]

  char* p = (char*)d_ws;
  _Float16* emb  = (_Float16*)p;  p += (size_t)32768 * 1024 * 2;   // 64 MiB
  _Float16* out0 = (_Float16*)p;  p += (size_t)32768 * 1024 * 2;   // 64 MiB
  _Float16* Wc   = (_Float16*)p;  p += (size_t)4 * 2048 * 1536 * 2;// 24 MiB
  float*    biasc= (float*)p;     p += (size_t)4 * 2048 * 4;       // 32 KiB
  _Float16* hbAll= (_Float16*)p;  p += (size_t)4 * 1048576 * 2;    // 8 MiB (4 bufs)
  float*    cbAll= (float*)p;     p += (size_t)2 * 1048576 * 4;    // 8 MiB (2 bufs)

  k_prepw<<<8192, 256, 0, stream>>>(Wih, Whh, Wc);
  k_prepb<<<32, 256, 0, stream>>>(bih, bhh, biasc);
  k_embed<<<32768, 256, 0, stream>>>(rt, re, rm, Ert, Ere, Erm, emb);
  k_init<<<4096, 256, 0, stream>>>(0, h0, c0, hbAll, cbAll);
  k_init<<<4096, 256, 0, stream>>>(1, h0, c0, hbAll + (size_t)2 * 1048576,
                                   cbAll + (size_t)1048576);

  // launch k: L0 step k (k<32) || L1 step k-1 (k>=1)
  for (int k = 0; k < 33; ++k) {
    k_step<<<dim3(32, 8, 2), 512, 0, stream>>>(k, k - 1, emb, out0, outs,
                                               hbAll, cbAll, Wc, biasc, hT, cT);
  }
}

// Round 4
// 2253.629 us; speedup vs baseline: 1.0114x; 1.0114x over previous
//
#include <hip/hip_runtime.h>
#include <hip/hip_bf16.h>
#include <stdint.h>

// ---------------------------------------------------------------------------
// EncoderBiLSTM on MI355X.
// RESET=32 => 16 independent chunks of 32 steps => 1024 independent rows/dir.
// Rows r = chunk*64 + b, t = chunk*32 + s.
// Per step, per layer: gates = [x_t | h] @ [Wih' | Whh']^T + bias (K=1536),
// fused fp16-MFMA GEMM (16x16x32) + in-epilogue LSTM cell update.
// Gate permutation: n = (j>>4)*64 + g*16 + (j&15), g in {i,f,g,o}.
//
// Layer pipelining: launch k runs {L0 step k} || {L1 step k-1} (gridDim.z=2).
// R4: T4 counted-vmcnt pipeline in k_step (raw s_barrier + vmcnt(4), never
// drain fresh stage) + T5 setprio around MFMA cluster. k_embed: 2 rows/thread.
// ---------------------------------------------------------------------------

typedef _Float16 half8 __attribute__((ext_vector_type(8)));
typedef _Float16 half4v __attribute__((ext_vector_type(4)));
typedef float float4v __attribute__((ext_vector_type(4)));

#define AS1C(p) ((const __attribute__((address_space(1))) void*)(p))
#define AS3(p)  ((__attribute__((address_space(3))) void*)(p))

__device__ __forceinline__ float sigm(float x){ return 1.0f/(1.0f + __expf(-x)); }
__device__ __forceinline__ float tanh_f(float x){ return 2.0f/(1.0f + __expf(-2.0f*x)) - 1.0f; }

// ---- embedding: emb[t][b][d] = (Ert[rt]+Ere[re]+Erm[rm]) as fp16 -----------
// 2 rows per thread (b and b+32) => 6 independent 16B gathers in flight.
__global__ __launch_bounds__(256) void k_embed(
    const int* __restrict__ rt, const int* __restrict__ re, const int* __restrict__ rm,
    const float* __restrict__ Ert, const float* __restrict__ Ere, const float* __restrict__ Erm,
    _Float16* __restrict__ emb)
{
  size_t idx = (size_t)blockIdx.x * 256 + threadIdx.x;   // 16384 blocks
  int dq = (int)(idx & 255);
  size_t bt = idx >> 8;                                  // b*512 + t, b<32
  size_t bt2 = bt + 16384;                               // b+32
  int a0 = rt[bt],  a1 = re[bt],  a2 = rm[bt];
  int b0 = rt[bt2], b1 = re[bt2], b2 = rm[bt2];
  float4 u0 = ((const float4*)Ert)[(size_t)a0 * 256 + dq];
  float4 u1 = ((const float4*)Ere)[(size_t)a1 * 256 + dq];
  float4 u2 = ((const float4*)Erm)[(size_t)a2 * 256 + dq];
  float4 w0 = ((const float4*)Ert)[(size_t)b0 * 256 + dq];
  float4 w1 = ((const float4*)Ere)[(size_t)b1 * 256 + dq];
  float4 w2 = ((const float4*)Erm)[(size_t)b2 * 256 + dq];
  half4v h, g;
  h[0] = (_Float16)(u0.x + u1.x + u2.x);
  h[1] = (_Float16)(u0.y + u1.y + u2.y);
  h[2] = (_Float16)(u0.z + u1.z + u2.z);
  h[3] = (_Float16)(u0.w + u1.w + u2.w);
  g[0] = (_Float16)(w0.x + w1.x + w2.x);
  g[1] = (_Float16)(w0.y + w1.y + w2.y);
  g[2] = (_Float16)(w0.z + w1.z + w2.z);
  g[3] = (_Float16)(w0.w + w1.w + w2.w);
  int b_ = (int)(bt >> 9), t_ = (int)(bt & 511);
  ((half4v*)emb)[((size_t)t_ * 64 + b_) * 256 + dq] = h;
  ((half4v*)emb)[((size_t)t_ * 64 + (b_ + 32)) * 256 + dq] = g;
}

// ---- weight prep: Wc[ld][n][k] fp16, k<1024 from Wih, else Whh; n permuted -
__global__ __launch_bounds__(256) void k_prepw(
    const float* __restrict__ Wih, const float* __restrict__ Whh,
    _Float16* __restrict__ Wc)
{
  int bid = blockIdx.x;            // 0..8191  = ld*2048 + n
  int ld = bid >> 11;
  int n  = bid & 2047;
  int g  = (n >> 4) & 3;
  int j  = ((n >> 6) << 4) | (n & 15);
  int srow = g * 512 + j;
  const float* sx = Wih + ((size_t)ld * 2048 + srow) * 1024;
  const float* sh = Whh + ((size_t)ld * 2048 + srow) * 512;
  _Float16* dst = Wc + ((size_t)ld * 2048 + n) * 1536;
  for (int k = threadIdx.x; k < 1536; k += 256)
    dst[k] = (_Float16)(k < 1024 ? sx[k] : sh[k - 1024]);
}

__global__ __launch_bounds__(256) void k_prepb(
    const float* __restrict__ bih, const float* __restrict__ bhh,
    float* __restrict__ biasc)
{
  int idx = blockIdx.x * 256 + threadIdx.x;   // 8192
  int ld = idx >> 11, n = idx & 2047;
  int g = (n >> 4) & 3;
  int j = ((n >> 6) << 4) | (n & 15);
  int srow = ld * 2048 + g * 512 + j;
  biasc[idx] = bih[srow] + bhh[srow];
}

// ---- state init per layer: chunk0 rows from h0/c0, rest zero ---------------
__global__ __launch_bounds__(256) void k_init(
    int layer, const float* __restrict__ h0, const float* __restrict__ c0,
    _Float16* __restrict__ hbuf, float* __restrict__ cbuf)
{
  int idx = blockIdx.x * 256 + threadIdx.x;   // 2*1024*512
  int dir = idx >> 19;
  int rj = idx & ((1 << 19) - 1);
  int r = rj >> 9, j = rj & 511;
  float hv = 0.f, cv = 0.f;
  if (r < 64) {
    size_t s0 = ((size_t)(layer * 2 + dir) * 64 + r) * 512 + j;
    hv = h0[s0]; cv = c0[s0];
  }
  hbuf[idx] = (_Float16)hv;
  cbuf[idx] = cv;
}

// ---- fused step: GEMM(K=1536) + LSTM cell update ---------------------------
// grid (32, 8, 2): x = nb (dir*16 + ntile), y = M-tile (128 rows), z = layer.
// 512 threads = 8 waves: wm = w>>1 (rows), wn = w&1 (64-col group).
__global__ __launch_bounds__(512, 4) void k_step(
    int s0, int s1,
    const _Float16* __restrict__ emb,    // [T*B][1024]
    _Float16* __restrict__ out0,         // [T*B][1024] (L0 dest / L1 src, fp16)
    float* __restrict__ outs,            // [B][T][1024] (L1 dest, fp32)
    _Float16* __restrict__ hbAll,        // 4 buffers: (layer*2+parity)*2^20 halves
    float* __restrict__ cbAll,           // 2 buffers: layer*2^20 floats
    const _Float16* __restrict__ Wc,     // [4][2048][1536]
    const float* __restrict__ biasc,     // [4][2048]
    float* __restrict__ hT, float* __restrict__ cT)
{
  const int layer = blockIdx.z;
  const int s = layer ? s1 : s0;
  if ((unsigned)s > 31u) return;         // boundary launches idle one z-half
                                         // (uniform per block; before any barrier)
  const _Float16* xsrc = layer ? out0 : emb;
  const _Float16* hin  = hbAll + ((size_t)(layer * 2 + (s & 1))) * 1048576;
  _Float16*       hout = hbAll + ((size_t)(layer * 2 + ((s & 1) ^ 1))) * 1048576;
  float*          cbuf = cbAll + (size_t)layer * 1048576;

  // 64 KiB LDS: two 32 KiB buffers; within a buffer: A [0,16K) B [16K,32K) bytes
  __shared__ __align__(16) _Float16 smem[32768];
  const int tid = threadIdx.x;
  const int w = tid >> 6, l = tid & 63;
  const int nb = blockIdx.x;
  const int m0 = blockIdx.y * 128;
  const int dir = nb >> 4;
  const int n0 = (nb & 15) * 128;
  const int ld = layer * 2 + dir;

  // staging descriptors: 32 wave-instrs (16 A + 16 B), 4 per wave.
  // LDS layout k-chunk-major: chunk c = kc*128 + row (16B each) -> byte c*16.
  const char* pX[4]; const char* pH[4]; uint32_t ldsoff[4];
  #pragma unroll
  for (int ii = 0; ii < 4; ++ii) {
    int instr = w * 4 + ii;
    if (instr < 16) {                       // A tile: 1024 chunks
      int c = instr * 64 + l;
      int row = c & 127, kc = c >> 7;
      int r = m0 + row;
      int erow = ((r >> 6) * 32 + s) * 64 + (r & 63);     // t*64 + b
      pX[ii] = (const char*)(xsrc + (size_t)erow * 1024 + kc * 8);
      // h-phase: global k maps to h col k-1024 => pre-bias ptr by -2048 BYTES
      pH[ii] = (const char*)(hin + ((size_t)dir * 1024 + r) * 512 + kc * 8) - 2048;
      ldsoff[ii] = (uint32_t)instr * 1024u;
    } else {                                // B tile: 1024 chunks
      int c = (instr - 16) * 64 + l;
      int nl = c & 127, kc = c >> 7;
      const char* p = (const char*)(Wc + ((size_t)ld * 2048 + n0 + nl) * 1536 + kc * 8);
      pX[ii] = p; pH[ii] = p;              // weight rows contiguous over full K
      ldsoff[ii] = 16384u + (uint32_t)(instr - 16) * 1024u;
    }
  }

  const int wm = w >> 1, wn = w & 1;
  float4v acc[2][4];
  const float4v vzero = {0.f, 0.f, 0.f, 0.f};
  #pragma unroll
  for (int mf = 0; mf < 2; ++mf)
    #pragma unroll
    for (int nf = 0; nf < 4; ++nf) acc[mf][nf] = vzero;

  auto stage = [&](int it, int buf) {
    const int k0 = it * 64;
    const bool isx = (it < 16);
    #pragma unroll
    for (int ii = 0; ii < 4; ++ii) {
      const char* src = (isx ? pX[ii] : pH[ii]) + (size_t)k0 * 2;
      __builtin_amdgcn_global_load_lds(AS1C(src),
          AS3(((char*)smem) + (size_t)buf * 32768 + ldsoff[ii]), 16, 0, 0);
    }
  };

  // T4 counted-vmcnt pipeline: per iter, wait only the OLD stage (vmcnt(4)),
  // leaving the fresh 4 loads in flight across the barrier. Two raw barriers:
  // (B) after vmcnt  -> all waves' stage(it) visible before compute(it);
  // (A) after lgkm(0)-> all waves done reading buf before next overwrite.
  stage(0, 0);
  #pragma unroll 2
  for (int it = 0; it < 24; ++it) {
    const int cur = it & 1;
    if (it < 23) {
      stage(it + 1, cur ^ 1);              // safe: barrier (A) of it-1 passed
      asm volatile("s_waitcnt vmcnt(4)" ::: "memory");
    } else {
      asm volatile("s_waitcnt vmcnt(0)" ::: "memory");
    }
    __builtin_amdgcn_sched_barrier(0);
    __builtin_amdgcn_s_barrier();          // (B)
    __builtin_amdgcn_sched_barrier(0);

    const _Float16* sA = smem + (size_t)cur * 16384;
    const _Float16* sB = sA + 8192;
    __builtin_amdgcn_s_setprio(1);
    #pragma unroll
    for (int kk = 0; kk < 64; kk += 32) {
      const int kcb = (kk >> 3) + (l >> 4);  // k-chunk for this lane
      half8 a[2], b[4];
      #pragma unroll
      for (int mf = 0; mf < 2; ++mf)
        a[mf] = *(const half8*)(sA + ((size_t)kcb * 128 + wm * 32 + mf * 16 + (l & 15)) * 8);
      #pragma unroll
      for (int nf = 0; nf < 4; ++nf)
        b[nf] = *(const half8*)(sB + ((size_t)kcb * 128 + wn * 64 + nf * 16 + (l & 15)) * 8);
      #pragma unroll
      for (int mf = 0; mf < 2; ++mf)
        #pragma unroll
        for (int nf = 0; nf < 4; ++nf)
          acc[mf][nf] = __builtin_amdgcn_mfma_f32_16x16x32_f16(a[mf], b[nf], acc[mf][nf], 0, 0, 0);
    }
    __builtin_amdgcn_s_setprio(0);
    asm volatile("s_waitcnt lgkmcnt(0)" ::: "memory");
    __builtin_amdgcn_sched_barrier(0);
    __builtin_amdgcn_s_barrier();          // (A)
    __builtin_amdgcn_sched_barrier(0);
  }

  // ---- epilogue: gates are in-lane (nf = gate), j = q*16 + (l&15) ----------
  const int q = (nb & 15) * 2 + wn;
  const int jj = l & 15;
  const int j = q * 16 + jj;
  const int bb_base = ld * 2048 + n0 + wn * 64;
  const float bias_i = biasc[bb_base + 0 * 16 + jj];
  const float bias_f = biasc[bb_base + 1 * 16 + jj];
  const float bias_g = biasc[bb_base + 2 * 16 + jj];
  const float bias_o = biasc[bb_base + 3 * 16 + jj];

  #pragma unroll
  for (int mf = 0; mf < 2; ++mf) {
    #pragma unroll
    for (int reg = 0; reg < 4; ++reg) {
      int r = m0 + wm * 32 + mf * 16 + (l >> 4) * 4 + reg;   // C/D row mapping
      float ip = acc[mf][0][reg] + bias_i;
      float fp = acc[mf][1][reg] + bias_f;
      float gp = acc[mf][2][reg] + bias_g;
      float op = acc[mf][3][reg] + bias_o;
      size_t cidx = ((size_t)dir * 1024 + r) * 512 + j;
      float cold = cbuf[cidx];
      float cn = sigm(fp) * cold + sigm(ip) * tanh_f(gp);
      float hn = sigm(op) * tanh_f(cn);
      cbuf[cidx] = cn;
      hout[cidx] = (_Float16)hn;
      int chunk = r >> 6, bb = r & 63;
      int t = chunk * 32 + s;
      if (layer == 0) {
        out0[((size_t)t * 64 + bb) * 1024 + dir * 512 + j] = (_Float16)hn;
      } else {
        outs[((size_t)bb * 512 + t) * 1024 + dir * 512 + j] = hn;
      }
      if (s == 31 && chunk == 15) {          // final carry -> hidden outputs
        size_t hidx = ((size_t)(layer * 2 + dir) * 64 + bb) * 512 + j;
        hT[hidx] = hn; cT[hidx] = cn;
      }
    }
  }
}

// ---------------------------------------------------------------------------
extern "C" void kernel_launch(void* const* d_in, const int* in_sizes, int n_in,
                              void* d_out, int out_size, void* d_ws, size_t ws_size,
                              hipStream_t stream)
{
  const int*   rt  = (const int*)d_in[0];
  const int*   re  = (const int*)d_in[1];
  const int*   rm  = (const int*)d_in[2];
  const float* h0  = (const float*)d_in[3];
  const float* c0  = (const float*)d_in[4];
  const float* Ert = (const float*)d_in[5];
  const float* Ere = (const float*)d_in[6];
  const float* Erm = (const float*)d_in[7];
  const float* Wih = (const float*)d_in[8];
  const float* Whh = (const float*)d_in[9];
  const float* bih = (const float*)d_in[10];
  const float* bhh = (const float*)d_in[11];

  float* outs = (float*)d_out;                       // [B][T][D]
  float* hT = outs + (size_t)64 * 512 * 1024;        // [4][B][H]
  float* cT = hT + (size_t)4 * 64 * 512;             // [4][B][H]

  char* p = (char*)d_ws;
  _Float16* emb  = (_Float16*)p;  p += (size_t)32768 * 1024 * 2;   // 64 MiB
  _Float16* out0 = (_Float16*)p;  p += (size_t)32768 * 1024 * 2;   // 64 MiB
  _Float16* Wc   = (_Float16*)p;  p += (size_t)4 * 2048 * 1536 * 2;// 24 MiB
  float*    biasc= (float*)p;     p += (size_t)4 * 2048 * 4;       // 32 KiB
  _Float16* hbAll= (_Float16*)p;  p += (size_t)4 * 1048576 * 2;    // 8 MiB (4 bufs)
  float*    cbAll= (float*)p;     p += (size_t)2 * 1048576 * 4;    // 8 MiB (2 bufs)

  k_prepw<<<8192, 256, 0, stream>>>(Wih, Whh, Wc);
  k_prepb<<<32, 256, 0, stream>>>(bih, bhh, biasc);
  k_embed<<<16384, 256, 0, stream>>>(rt, re, rm, Ert, Ere, Erm, emb);
  k_init<<<4096, 256, 0, stream>>>(0, h0, c0, hbAll, cbAll);
  k_init<<<4096, 256, 0, stream>>>(1, h0, c0, hbAll + (size_t)2 * 1048576,
                                   cbAll + (size_t)1048576);

  // launch k: L0 step k (k<32) || L1 step k-1 (k>=1)
  for (int k = 0; k < 33; ++k) {
    k_step<<<dim3(32, 8, 2), 512, 0, stream>>>(k, k - 1, emb, out0, outs,
                                               hbAll, cbAll, Wc, biasc, hT, cT);
  }
}